// Round 11
// baseline (490.781 us; speedup 1.0000x reference)
//
#include <hip/hip_runtime.h>
#include <hip/hip_bf16.h>
#include <math.h>
#include <stdint.h>

// B=8, P1=256 -> T=512 concat rows, C=1024, H=4096
#define TB_ 8
#define TT_ 512
#define TC_ 1024
// wkv chunked scan: 32 chunks of 16 steps
#define WKV_NCH 32
#define WKV_L 16

typedef __attribute__((ext_vector_type(8))) short bf16x8;
typedef __attribute__((ext_vector_type(4))) short s16x4;
typedef __attribute__((ext_vector_type(4))) float f32x4;

__device__ __forceinline__ float b2f(short u) {
  union { unsigned int i; float f; } x;
  x.i = ((unsigned int)(unsigned short)u) << 16;
  return x.f;
}
__device__ __forceinline__ short f2b(float f) {
  __hip_bfloat16 h = __float2bfloat16(f);  // RNE
  return __builtin_bit_cast(short, h);
}
__device__ __forceinline__ float sigm(float x) { return 1.0f / (1.0f + expf(-x)); }

// LIF over 4 identical inputs (closed form of the reference scan), TAU=2, VTH=1
__device__ __forceinline__ float lif4(float a) {
  float v = 0.0f, acc = 0.0f;
#pragma unroll
  for (int i = 0; i < 4; ++i) {
    v += (a - v) * 0.5f;
    float s = (v >= 1.0f) ? 1.0f : 0.0f;
    acc += s;
    v *= (1.0f - s);
  }
  return acc * 0.25f;
}

__device__ __forceinline__ void gload16(const void* g, void* l) {
  __builtin_amdgcn_global_load_lds(
      (__attribute__((address_space(1))) void*)(g),
      (__attribute__((address_space(3))) void*)(l), 16, 0, 0);
}

// counted vmcnt wait (compile-time immediate)
template <int N>
__device__ __forceinline__ void waitv() {
  if constexpr (N == 0)  asm volatile("s_waitcnt vmcnt(0)" ::: "memory");
  else if constexpr (N == 2)  asm volatile("s_waitcnt vmcnt(2)" ::: "memory");
  else if constexpr (N == 3)  asm volatile("s_waitcnt vmcnt(3)" ::: "memory");
  else if constexpr (N == 4)  asm volatile("s_waitcnt vmcnt(4)" ::: "memory");
  else if constexpr (N == 6)  asm volatile("s_waitcnt vmcnt(6)" ::: "memory");
  else if constexpr (N == 8)  asm volatile("s_waitcnt vmcnt(8)" ::: "memory");
  else static_assert(N == 0, "unsupported vmcnt");
}
__device__ __forceinline__ void barrier_() {
  asm volatile("s_barrier" ::: "memory");
}

// ---------------- elementwise kernels ----------------

// fused concat + LayerNorm: row of xc = (t<256 ? x : rt); writes XC (f32 copy)
// and LN output (bf16). One 256-thread block per row (4096 rows).
__global__ __launch_bounds__(256) void ln_first(const float* __restrict__ x,
                                                const float* __restrict__ rt,
                                                float* __restrict__ xc,
                                                short* __restrict__ dst) {
  __shared__ float red[256];
  int row = blockIdx.x;  // b*512 + t
  int t = row & 511, b = row >> 9;
  const float* src = (t < 256) ? x + (int64_t)(b * 256 + t) * TC_
                               : rt + (int64_t)(t - 256) * TC_;
  float4 v = ((const float4*)src)[threadIdx.x];
  ((float4*)(xc + (int64_t)row * TC_))[threadIdx.x] = v;
  red[threadIdx.x] = v.x + v.y + v.z + v.w;
  __syncthreads();
  for (int off = 128; off > 0; off >>= 1) {
    if (threadIdx.x < off) red[threadIdx.x] += red[threadIdx.x + off];
    __syncthreads();
  }
  float mean = red[0] * (1.0f / 1024.0f);
  __syncthreads();
  float dx = v.x - mean, dy = v.y - mean, dz = v.z - mean, dw = v.w - mean;
  red[threadIdx.x] = dx * dx + dy * dy + dz * dz + dw * dw;
  __syncthreads();
  for (int off = 128; off > 0; off >>= 1) {
    if (threadIdx.x < off) red[threadIdx.x] += red[threadIdx.x + off];
    __syncthreads();
  }
  float rs = 1.0f / sqrtf(red[0] * (1.0f / 1024.0f) + 1e-6f);
  s16x4 o;
  o.x = f2b(dx * rs); o.y = f2b(dy * rs); o.z = f2b(dz * rs); o.w = f2b(dw * rs);
  *(s16x4*)(dst + (int64_t)row * TC_ + threadIdx.x * 4) = o;
}

// LayerNorm each row (C=1024 f32) -> bf16. One 256-thread block per row.
__global__ __launch_bounds__(256) void ln_rows_b(const float* __restrict__ src,
                                                 short* __restrict__ dst) {
  __shared__ float red[256];
  int64_t row = blockIdx.x;
  float4 v = ((const float4*)(src + row * TC_))[threadIdx.x];
  red[threadIdx.x] = v.x + v.y + v.z + v.w;
  __syncthreads();
  for (int off = 128; off > 0; off >>= 1) {
    if (threadIdx.x < off) red[threadIdx.x] += red[threadIdx.x + off];
    __syncthreads();
  }
  float mean = red[0] * (1.0f / 1024.0f);
  __syncthreads();
  float dx = v.x - mean, dy = v.y - mean, dz = v.z - mean, dw = v.w - mean;
  red[threadIdx.x] = dx * dx + dy * dy + dz * dz + dw * dw;
  __syncthreads();
  for (int off = 128; off > 0; off >>= 1) {
    if (threadIdx.x < off) red[threadIdx.x] += red[threadIdx.x + off];
    __syncthreads();
  }
  float rs = 1.0f / sqrtf(red[0] * (1.0f / 1024.0f) + 1e-6f);
  s16x4 o;
  o.x = f2b(dx * rs); o.y = f2b(dy * rs); o.z = f2b(dz * rs); o.w = f2b(dw * rs);
  *(s16x4*)(dst + row * TC_ + threadIdx.x * 4) = o;
}

// time-mix blends from bf16 LN. 8 elems/thread; i over B*T*C/8.
__global__ __launch_bounds__(256) void mix3_b(const short* __restrict__ ln,
                                              const float* __restrict__ tk,
                                              const float* __restrict__ tv,
                                              const float* __restrict__ tr,
                                              short* __restrict__ xk,
                                              short* __restrict__ xv,
                                              short* __restrict__ xr) {
  int i = blockIdx.x * 256 + threadIdx.x;  // short8 index
  int c8 = i & 127;
  int t = (i >> 7) & 511;
  bf16x8 h = *(const bf16x8*)(ln + (int64_t)i * 8);
  bf16x8 s = {};
  if (t > 0) s = *(const bf16x8*)(ln + (int64_t)(i - 128) * 8);
  bf16x8 ok, ov, orr;
#pragma unroll
  for (int e = 0; e < 8; ++e) {
    float hf = b2f(h[e]), sf = b2f(s[e]);
    int c = c8 * 8 + e;
    float mk = tk[c], mv = tv[c], mr = tr[c];
    ok[e] = f2b(hf * mk + sf * (1.0f - mk));
    ov[e] = f2b(hf * mv + sf * (1.0f - mv));
    orr[e] = f2b(hf * mr + sf * (1.0f - mr));
  }
  *(bf16x8*)(xk + (int64_t)i * 8) = ok;
  *(bf16x8*)(xv + (int64_t)i * 8) = ov;
  *(bf16x8*)(xr + (int64_t)i * 8) = orr;
}

__global__ __launch_bounds__(256) void mix2_b(const short* __restrict__ ln,
                                              const float* __restrict__ tk,
                                              const float* __restrict__ tr,
                                              short* __restrict__ xk,
                                              short* __restrict__ xr) {
  int i = blockIdx.x * 256 + threadIdx.x;
  int c8 = i & 127;
  int t = (i >> 7) & 511;
  bf16x8 h = *(const bf16x8*)(ln + (int64_t)i * 8);
  bf16x8 s = {};
  if (t > 0) s = *(const bf16x8*)(ln + (int64_t)(i - 128) * 8);
  bf16x8 ok, orr;
#pragma unroll
  for (int e = 0; e < 8; ++e) {
    float hf = b2f(h[e]), sf = b2f(s[e]);
    int c = c8 * 8 + e;
    float mk = tk[c], mr = tr[c];
    ok[e] = f2b(hf * mk + sf * (1.0f - mk));
    orr[e] = f2b(hf * mr + sf * (1.0f - mr));
  }
  *(bf16x8*)(xk + (int64_t)i * 8) = ok;
  *(bf16x8*)(xr + (int64_t)i * 8) = orr;
}

// f32 -> bf16, 8 elems/thread (used for Wck after its slot frees up)
__global__ __launch_bounds__(256) void cvt_b(const float* __restrict__ src,
                                             short* __restrict__ dst) {
  int64_t i = (int64_t)(blockIdx.x * 256 + threadIdx.x) * 8;
  float4 a = *(const float4*)(src + i);
  float4 b = *(const float4*)(src + i + 4);
  bf16x8 o;
  o[0] = f2b(a.x); o[1] = f2b(a.y); o[2] = f2b(a.z); o[3] = f2b(a.w);
  o[4] = f2b(b.x); o[5] = f2b(b.y); o[6] = f2b(b.z); o[7] = f2b(b.w);
  *(bf16x8*)(dst + i) = o;
}

// ONE launch: convert 8 weight arrays f32->bf16 + fused Wam row-sum.
__global__ __launch_bounds__(256) void cvt_all(
    const float* __restrict__ Wk, const float* __restrict__ Wv,
    const float* __restrict__ Wr, const float* __restrict__ Wo,
    const float* __restrict__ Wcr, const float* __restrict__ Wcv,
    const float* __restrict__ Wrm, const float* __restrict__ Wam,
    short* __restrict__ bWk, short* __restrict__ bWv, short* __restrict__ bWr,
    short* __restrict__ bWo, short* __restrict__ bWcr, short* __restrict__ bWcv,
    short* __restrict__ bWrm, short* __restrict__ bWam,
    float* __restrict__ S) {
  int bid = blockIdx.x;
  if (bid >= 4864) {  // Wam row-sums: 4 rows per block, 64 lanes per row
    int row = (bid - 4864) * 4 + (threadIdx.x >> 6);
    int lane = threadIdx.x & 63;
    float4 v = ((const float4*)(Wam + (int64_t)row * 256))[lane];
    float s = v.x + v.y + v.z + v.w;
    for (int off = 32; off > 0; off >>= 1) s += __shfl_down(s, off);
    if (lane == 0) S[row] = s;
    return;
  }
  const float* src; short* dst; int base;
  if (bid < 512)       { src = Wk;  dst = bWk;  base = bid; }
  else if (bid < 1024) { src = Wv;  dst = bWv;  base = bid - 512; }
  else if (bid < 1536) { src = Wr;  dst = bWr;  base = bid - 1024; }
  else if (bid < 2048) { src = Wo;  dst = bWo;  base = bid - 1536; }
  else if (bid < 2560) { src = Wcr; dst = bWcr; base = bid - 2048; }
  else if (bid < 4608) { src = Wcv; dst = bWcv; base = bid - 2560; }
  else if (bid < 4736) { src = Wrm; dst = bWrm; base = bid - 4608; }
  else                 { src = Wam; dst = bWam; base = bid - 4736; }
  int64_t i = ((int64_t)base * 256 + threadIdx.x) * 8;
  float4 a = *(const float4*)(src + i);
  float4 b = *(const float4*)(src + i + 4);
  bf16x8 o;
  o[0] = f2b(a.x); o[1] = f2b(a.y); o[2] = f2b(a.z); o[3] = f2b(a.w);
  o[4] = f2b(b.x); o[5] = f2b(b.y); o[6] = f2b(b.z); o[7] = f2b(b.w);
  *(bf16x8*)(dst + i) = o;
}

// rtok rows (per b: rows 256..511 of XC) f32 -> bf16 contiguous (B,256,C)
__global__ __launch_bounds__(256) void cvt_rtok(const float* __restrict__ xc,
                                                short* __restrict__ dst) {
  int i = blockIdx.x * 256 + threadIdx.x;  // short8 idx
  int b = i >> 15;
  int rem = i & 32767;
  const float* s = xc + (int64_t)b * 524288 + 262144 + (int64_t)rem * 8;
  float4 a = *(const float4*)s;
  float4 c = *(const float4*)(s + 4);
  bf16x8 o;
  o[0] = f2b(a.x); o[1] = f2b(a.y); o[2] = f2b(a.z); o[3] = f2b(a.w);
  o[4] = f2b(c.x); o[5] = f2b(c.y); o[6] = f2b(c.z); o[7] = f2b(c.w);
  *(bf16x8*)(dst + (int64_t)i * 8) = o;
}

// ---------------- wkv chunked parallel scan ----------------
__global__ __launch_bounds__(256) void wkv_p1(const float* __restrict__ td,
                                              const short* __restrict__ K,
                                              const short* __restrict__ V,
                                              float* __restrict__ Ca,
                                              float* __restrict__ Da,
                                              float* __restrict__ Qa) {
  int bx = blockIdx.x;  // [ch:5][b:3][cg:2]
  int ch = bx >> 5;
  int b = (bx >> 2) & 7;
  int c = (bx & 3) * 256 + threadIdx.x;
  float w = -expf(td[c]);
  float aa = 0.0f, bb = 0.0f, pp = -1e38f;
  int64_t base = ((int64_t)b * TT_ + ch * WKV_L) * TC_ + c;
#pragma unroll
  for (int t = 0; t < WKV_L; ++t) {
    int64_t o = base + (int64_t)t * TC_;
    float kt = b2f(K[o]), vt = b2f(V[o]);
    float ww2 = pp + w;
    float p2 = fmaxf(ww2, kt);
    float e1 = expf(ww2 - p2);
    float e2 = expf(kt - p2);
    aa = e1 * aa + e2 * vt;
    bb = e1 * bb + e2;
    pp = p2;
  }
  int idx = ch * 8192 + b * 1024 + c;
  Ca[idx] = aa; Da[idx] = bb; Qa[idx] = pp;
}

__global__ __launch_bounds__(256) void wkv_p2(const float* __restrict__ td,
                                              const float* __restrict__ Ca,
                                              const float* __restrict__ Da,
                                              const float* __restrict__ Qa,
                                              float* __restrict__ Aa,
                                              float* __restrict__ Ba,
                                              float* __restrict__ Pa) {
  int i = blockIdx.x * 256 + threadIdx.x;  // 0..8191 = b*1024+c
  int c = i & (TC_ - 1);
  float wL = -expf(td[c]) * (float)WKV_L;
  float aa = 0.0f, bb = 0.0f, pp = -1e38f;
#pragma unroll 4
  for (int ch = 0; ch < WKV_NCH; ++ch) {
    int idx = ch * 8192 + i;
    Aa[idx] = aa; Ba[idx] = bb; Pa[idx] = pp;
    float ppw = pp + wL;
    float q = Qa[idx];
    float p2 = fmaxf(ppw, q);
    float ea = expf(ppw - p2);
    float eb = expf(q - p2);
    aa = aa * ea + Ca[idx] * eb;
    bb = bb * ea + Da[idx] * eb;
    pp = p2;
  }
}

__global__ __launch_bounds__(256) void wkv_p3(const float* __restrict__ td,
                                              const float* __restrict__ tf,
                                              const short* __restrict__ K,
                                              const short* __restrict__ V,
                                              const short* __restrict__ SR,
                                              short* __restrict__ SRY,
                                              const float* __restrict__ Aa,
                                              const float* __restrict__ Ba,
                                              const float* __restrict__ Pa) {
  int bx = blockIdx.x;
  int ch = bx >> 5;
  int b = (bx >> 2) & 7;
  int c = (bx & 3) * 256 + threadIdx.x;
  float w = -expf(td[c]);
  float u = tf[c];
  int idx = ch * 8192 + b * 1024 + c;
  float aa = Aa[idx], bb = Ba[idx], pp = Pa[idx];
  int64_t base = ((int64_t)b * TT_ + ch * WKV_L) * TC_ + c;
#pragma unroll
  for (int t = 0; t < WKV_L; ++t) {
    int64_t o = base + (int64_t)t * TC_;
    float kt = b2f(K[o]), vt = b2f(V[o]);
    float ww = u + kt;
    float p = fmaxf(pp, ww);
    float E1 = expf(pp - p);
    float E2 = expf(ww - p);
    float y = (E1 * aa + E2 * vt) / (E1 * bb + E2);
    SRY[o] = f2b(y * b2f(SR[o]));
    float ww2 = pp + w;
    float p2 = fmaxf(ww2, kt);
    float e1 = expf(ww2 - p2);
    float e2 = expf(kt - p2);
    aa = e1 * aa + e2 * vt;
    bb = e1 * bb + e2;
    pp = p2;
  }
}

// ---------------- direct-from-global MFMA GEMM (N=1024 shapes) ----------
// One wave per block (64 threads), 64x64 output tile. NO LDS, NO barriers:
// MFMA fragments gathered straight global->VGPR. Gather is line-efficient:
// lanes 0-15 hit 16 consecutive rows at k0, lanes 16-63 the SAME 64B lines
// at k0+8/16/24. Register double-buffer (named sets a0/a1) so step t+1's 8
// loads fly under step t's 16 MFMAs (~256 cyc covers ~200 cyc L2 latency).
// Removes the LDS-port serialization (384 cyc/step) that bound gemm_bf16 at
// 1 blk/CU. B (2 MB weights) is L2-resident; A re-reads hit L1/L2.
template <int EPI>
__global__ __launch_bounds__(64) void gemm_direct(
    const short* __restrict__ A, const short* __restrict__ B,
    void* __restrict__ Cp, int M, int N, int K,
    int64_t sA, int64_t sB, int64_t sC,
    const float* __restrict__ e0, const float* __restrict__ e1,
    const float* __restrict__ e2, const void* __restrict__ e3, int64_t sE) {
  const int lane = threadIdx.x;
  // bijective XCD chunked swizzle (m204)
  const unsigned gx = gridDim.x, gy = gridDim.y;
  const unsigned nwg = gx * gy * gridDim.z;
  const unsigned lin = blockIdx.x + gx * (blockIdx.y + gy * blockIdx.z);
  const unsigned cs = nwg >> 3;
  const unsigned nl = (lin & 7) * cs + (lin >> 3);
  const unsigned bxs = nl % gx;
  const unsigned tmp = nl / gx;
  const unsigned bys = tmp % gy;
  const unsigned bz = tmp / gy;

  const int brow = bys * 64;
  const int bcol = bxs * 64;
  const short* Ab = A + bz * sA;
  const short* Bb = B + bz * sB;

  // fragment base pointers: frag f, lane l -> row f*16+(l&15), k (l>>4)*8
  const short* pA[4];
  const short* pB[4];
#pragma unroll
  for (int f = 0; f < 4; ++f) {
    pA[f] = Ab + (int64_t)(brow + f * 16 + (lane & 15)) * K + (lane >> 4) * 8;
    pB[f] = Bb + (int64_t)(bcol + f * 16 + (lane & 15)) * K + (lane >> 4) * 8;
  }

  f32x4 acc[4][4] = {};
  bf16x8 a0[4], b0[4], a1[4], b1[4];

  auto loadf = [&](bf16x8* fa, bf16x8* fb, int k0) {
#pragma unroll
    for (int f = 0; f < 4; ++f) fa[f] = *(const bf16x8*)(pA[f] + k0);
#pragma unroll
    for (int f = 0; f < 4; ++f) fb[f] = *(const bf16x8*)(pB[f] + k0);
  };
  auto comp = [&](bf16x8* fa, bf16x8* fb) {
#pragma unroll
    for (int m = 0; m < 4; ++m)
#pragma unroll
      for (int n = 0; n < 4; ++n)
        acc[m][n] = __builtin_amdgcn_mfma_f32_16x16x32_bf16(fa[m], fb[n],
                                                            acc[m][n], 0, 0, 0);
  };

  const int nst = K / 32;  // even, >= 4 for all uses
  loadf(a0, b0, 0);
  int t = 0;
  for (; t + 2 < nst; t += 2) {
    loadf(a1, b1, (t + 1) * 32);
    comp(a0, b0);
    loadf(a0, b0, (t + 2) * 32);
    comp(a1, b1);
  }
  loadf(a1, b1, (t + 1) * 32);
  comp(a0, b0);
  comp(a1, b1);

  const int r0 = brow + (lane >> 4) * 4;
  const int c0 = bcol + (lane & 15);
#pragma unroll
  for (int m = 0; m < 4; ++m) {
#pragma unroll
    for (int j = 0; j < 4; ++j) {
      int row = r0 + m * 16 + j;
#pragma unroll
      for (int n = 0; n < 4; ++n) {
        int col = c0 + n * 16;
        float v = acc[m][n][j];
        int64_t idx = (int64_t)row * N + col;
        if (EPI == 1) {
          ((short*)Cp)[bz * sC + idx] = f2b(sigm(v));
        } else if (EPI == 4) {
          float* XC = (float*)Cp;
          XC[idx] = XC[idx] + lif4(v);
        } else if (EPI == 5) {
          float* XC = (float*)Cp;
          float srr = b2f(((const short*)e3)[idx]);
          XC[idx] = XC[idx] + lif4(v * srr);
        } else if (EPI == 6) {
          ((short*)Cp)[bz * sC + idx] = f2b(bz == 2 ? sigm(v) : v);
        }
      }
    }
  }
}

// ---------------- LDS MFMA GEMM (multi-block/CU shapes: H + tails) -------
template <int BM, int BN, int EPI, int D, int MINW>
__global__ __launch_bounds__(256, MINW) void gemm_bf16(
    const short* __restrict__ A, const short* __restrict__ B,
    void* __restrict__ Cp, int M, int N, int K,
    int64_t sA, int64_t sB, int64_t sC,
    const float* __restrict__ e0, const float* __restrict__ e1,
    const float* __restrict__ e2, const void* __restrict__ e3, int64_t sE) {
  constexpr int MF = BM / 32;
  constexpr int NF = BN / 32;
  constexpr int ASLOT = BM / 64;
  constexpr int BSLOT = BN / 64;
  constexpr int NL = ASLOT + BSLOT;
  constexpr int SBUF = (BM + BN) * 32;
  __shared__ short lds[D * SBUF];
  const int tid = threadIdx.x;

  const unsigned gx = gridDim.x, gy = gridDim.y;
  const unsigned nwg = gx * gy * gridDim.z;
  const unsigned lin = blockIdx.x + gx * (blockIdx.y + gy * blockIdx.z);
  const unsigned cs = nwg >> 3;
  const unsigned nl = (lin & 7) * cs + (lin >> 3);
  const unsigned bxs = nl % gx;
  const unsigned tmp = nl / gx;
  const unsigned bys = tmp % gy;
  const unsigned bz = tmp / gy;

  const int brow = bys * BM;
  const int bcol = bxs * BN;
  const short* Ab = A + bz * sA;
  const short* Bb = B + bz * sB;

  const int srow = ((tid >> 6) << 4) + (tid & 15);
  const int skc = ((tid >> 4) & 3) * 8;
  const short* gA[ASLOT];
  const short* gB[BSLOT];
#pragma unroll
  for (int s = 0; s < ASLOT; ++s)
    gA[s] = Ab + (int64_t)(brow + s * 64 + srow) * K + skc;
#pragma unroll
  for (int s = 0; s < BSLOT; ++s)
    gB[s] = Bb + (int64_t)(bcol + s * 64 + srow) * K + skc;

  const int lane = tid & 63, wid = tid >> 6;
  const int wr = wid >> 1, wc = wid & 1;

  f32x4 acc[MF][NF] = {};

  auto stage = [&](int buf, int k0) {
    short* d = lds + buf * SBUF;
#pragma unroll
    for (int s = 0; s < ASLOT; ++s)
      gload16(gA[s] + k0, d + s * 2048 + tid * 8);
#pragma unroll
    for (int s = 0; s < BSLOT; ++s)
      gload16(gB[s] + k0, d + BM * 32 + s * 2048 + tid * 8);
  };
  auto compute = [&](int buf) {
    const short* base = lds + buf * SBUF;
    bf16x8 af[MF], bfv[NF];
#pragma unroll
    for (int m = 0; m < MF; ++m)
      af[m] = *(const bf16x8*)(base + (wr * MF + m) * 512 + lane * 8);
#pragma unroll
    for (int n = 0; n < NF; ++n)
      bfv[n] = *(const bf16x8*)(base + BM * 32 + (wc * NF + n) * 512 + lane * 8);
#pragma unroll
    for (int m = 0; m < MF; ++m)
#pragma unroll
      for (int n = 0; n < NF; ++n)
        acc[m][n] = __builtin_amdgcn_mfma_f32_16x16x32_bf16(af[m], bfv[n],
                                                            acc[m][n], 0, 0, 0);
  };

  const int nst = K / 32;
#pragma unroll
  for (int d = 0; d < D - 1; ++d) stage(d, d * 32);
  for (int t = 0; t <= nst - D; ++t) {
    stage((t + D - 1) & (D - 1), (t + D - 1) * 32);
    waitv<(D - 1) * NL>();
    barrier_();
    compute(t & (D - 1));
    barrier_();
  }
  {
    int t = nst - D + 1;
    if constexpr (D >= 4) {
      waitv<2 * NL>(); barrier_(); compute(t & (D - 1)); barrier_(); ++t;
      waitv<1 * NL>(); barrier_(); compute(t & (D - 1)); barrier_(); ++t;
    }
    waitv<0>(); barrier_(); compute(t & (D - 1));
  }

  const int r0 = brow + wr * (BM / 2) + (lane >> 4) * 4;
  const int c0 = bcol + wc * (BN / 2) + (lane & 15);
#pragma unroll
  for (int m = 0; m < MF; ++m) {
#pragma unroll
    for (int j = 0; j < 4; ++j) {
      int row = r0 + m * 16 + j;
#pragma unroll
      for (int n = 0; n < NF; ++n) {
        int col = c0 + n * 16;
        float v = acc[m][n][j];
        int64_t idx = (int64_t)row * N + col;
        if (EPI == 0) {
          ((short*)Cp)[bz * sC + idx] = f2b(v);
        } else if (EPI == 2) {
          v = fmaxf(v, 0.0f);
          ((short*)Cp)[bz * sC + idx] = f2b(v * v);
        } else if (EPI == 3) {
          float r2 = v + e0[row] * e1[col] + e2[col];
          float xo = ((const float*)e3)[bz * sE + idx];
          ((float*)Cp)[bz * sC + idx] = xo * (1.0f + r2);
        }
      }
    }
  }
}

// ---------------- launch ----------------
extern "C" void kernel_launch(void* const* d_in, const int* in_sizes, int n_in,
                              void* d_out, int out_size, void* d_ws,
                              size_t ws_size, hipStream_t stream) {
  const float* x   = (const float*)d_in[0];
  const float* rt  = (const float*)d_in[1];
  const float* td  = (const float*)d_in[2];
  const float* tf  = (const float*)d_in[3];
  const float* tmk = (const float*)d_in[4];
  const float* tmv = (const float*)d_in[5];
  const float* tmr = (const float*)d_in[6];
  const float* Wk  = (const float*)d_in[7];
  const float* Wv  = (const float*)d_in[8];
  const float* Wr  = (const float*)d_in[9];
  const float* Wo  = (const float*)d_in[10];
  const float* cmk = (const float*)d_in[11];
  const float* cmr = (const float*)d_in[12];
  const float* Wck = (const float*)d_in[13];
  const float* Wcv = (const float*)d_in[14];
  const float* Wcr = (const float*)d_in[15];
  const float* Wrm = (const float*)d_in[16];
  const float* brm = (const float*)d_in[17];
  const float* Wam = (const float*)d_in[18];
  const float* bam = (const float*)d_in[19];
  float* out = (float*)d_out;

  const size_t MB = 1ull << 20;
  uint8_t* W8 = (uint8_t*)d_ws;
  float* XC   = (float*)(W8);                        // 0-16 residual f32
  short* L    = (short*)(W8 + 16 * MB);              // 16-24 ln out
  short* S1   = (short*)(W8 + 24 * MB);              // 24-32 xk / SRY / SRR
  short* S2   = (short*)(W8 + 32 * MB);              // 32-40 xv / xk2 / rtok,Mt
  short* S3   = (short*)(W8 + 40 * MB);              // 40-48 xr / xr2 / bWck
  short* bWcv = (short*)(W8 + 48 * MB);              // 48-56
  short* bWk  = (short*)(W8 + 56 * MB);              // 56-62 bWk,bWv,bWr contig
  short* bWo  = (short*)(W8 + 62 * MB);
  short* bWcr = (short*)(W8 + 64 * MB);
  short* bWrm = (short*)(W8 + 66 * MB);              // 0.5 MB
  short* bWam = (short*)(W8 + 66 * MB + 512 * 1024); // 0.5 MB
  short* KK   = (short*)(W8 + 67 * MB);              // 67-75
  short* VV   = (short*)(W8 + 75 * MB);              // 75-83
  short* RR   = (short*)(W8 + 83 * MB);              // 83-91
  float* Ca   = (float*)(W8 + 91 * MB);
  float* Da   = (float*)(W8 + 92 * MB);
  float* Qa   = (float*)(W8 + 93 * MB);
  float* Aa   = (float*)(W8 + 94 * MB);
  float* Ba   = (float*)(W8 + 95 * MB);
  float* Pa   = (float*)(W8 + 96 * MB);
  short* SRY  = S1;
  short* xk2  = S2;
  short* xr2  = S3;
  short* SRR  = S1;
  short* bWck = S3;                                  // after SRR GEMM
  short* H16  = KK;                                  // 67-99 (32 MB)
  short* rtok = S2;                                  // 32-36
  short* Mt   = (short*)(W8 + 36 * MB);              // 36-37
  float* Sb   = (float*)(W8 + 99 * MB);              // 4 KB, aliases nothing

  dim3 blk(256);
  const int NV8 = 2048;

  // 0) ALL weight conversions + Wam row-sum in one launch
  cvt_all<<<5120, blk, 0, stream>>>(Wk, Wv, Wr, Wo, Wcr, Wcv, Wrm, Wam,
                                    bWk, bWk + 1048576, bWk + 2097152, bWo,
                                    bWcr, bWcv, bWrm, bWam, Sb);

  // 1) fused concat+ln1 -> XC, L; mixes -> S1,S2,S3
  ln_first<<<TB_ * TT_, blk, 0, stream>>>(x, rt, XC, L);
  mix3_b<<<NV8, blk, 0, stream>>>(L, tmk, tmv, tmr, S1, S2, S3);

  // 2) fused z=3 time-mix: KK = xk*Wk^T, VV = xv*Wv^T, RR = sigm(xr*Wr^T)
  gemm_direct<6><<<dim3(16, 64, 3), dim3(64), 0, stream>>>(
      S1, bWk, KK, 4096, 1024, 1024, 4194304, 1048576, 4194304,
      nullptr, nullptr, nullptr, nullptr, 0);
  // 3) wkv chunked scan -> SRY (=S1)
  wkv_p1<<<WKV_NCH * TB_ * 4, blk, 0, stream>>>(td, KK, VV, Ca, Da, Qa);
  wkv_p2<<<32, blk, 0, stream>>>(td, Ca, Da, Qa, Aa, Ba, Pa);
  wkv_p3<<<WKV_NCH * TB_ * 4, blk, 0, stream>>>(td, tf, KK, VV, RR, SRY,
                                                Aa, Ba, Pa);
  // 4) att: XC += lif(SRY*Wo^T)
  gemm_direct<4><<<dim3(16, 64, 1), dim3(64), 0, stream>>>(
      SRY, bWo, XC, 4096, 1024, 1024, 0, 0, 0,
      nullptr, nullptr, nullptr, nullptr, 0);
  // 5) ln2 -> L; mix2 -> xk2(S2), xr2(S3)
  ln_rows_b<<<TB_ * TT_, blk, 0, stream>>>(XC, L);
  mix2_b<<<NV8, blk, 0, stream>>>(L, cmk, cmr, xk2, xr2);
  // 6) SRR = sigm(xr2*Wcr^T) -> S1
  gemm_direct<1><<<dim3(16, 64, 1), dim3(64), 0, stream>>>(
      xr2, bWcr, SRR, 4096, 1024, 1024, 0, 0, 0,
      nullptr, nullptr, nullptr, nullptr, 0);
  // 7) Wck -> bf16 into now-dead xr2 slot
  cvt_b<<<2048, blk, 0, stream>>>(Wck, bWck);
  // 8) H = relu^2(xk2*Wck^T) -> H16 (grid 1024 = 4 blk/CU, LDS path)
  gemm_bf16<128, 128, 2, 2, 4><<<dim3(32, 32, 1), blk, 0, stream>>>(
      xk2, bWck, H16, 4096, 4096, 1024, 0, 0, 0,
      nullptr, nullptr, nullptr, nullptr, 0);
  // 9) XC += lif(SRR * (H*Wcv^T))  (K=4096, direct)
  gemm_direct<5><<<dim3(16, 64, 1), dim3(64), 0, stream>>>(
      H16, bWcv, XC, 4096, 1024, 4096, 0, 0, 0,
      nullptr, nullptr, nullptr, SRR, 0);
  // 10) tail
  cvt_rtok<<<1024, blk, 0, stream>>>(XC, rtok);
  gemm_bf16<64, 64, 0, 2, 2><<<dim3(4, 4, 8), blk, 0, stream>>>(
      bWrm, rtok, Mt, 256, 256, 1024, 0, (int64_t)256 * 1024,
      (int64_t)256 * 256, nullptr, nullptr, nullptr, nullptr, 0);
  gemm_bf16<64, 64, 3, 2, 2><<<dim3(16, 4, 8), blk, 0, stream>>>(
      Mt, bWam, out, 256, 1024, 256, (int64_t)256 * 256, 0,
      (int64_t)256 * 1024, brm, Sb, bam, XC, (int64_t)512 * 1024);
}

// Round 13
// 343.418 us; speedup vs baseline: 1.4291x; 1.4291x over previous
//
#include <hip/hip_runtime.h>
#include <hip/hip_bf16.h>
#include <math.h>
#include <stdint.h>

// B=8, P1=256 -> T=512 concat rows, C=1024, H=4096
#define TB_ 8
#define TT_ 512
#define TC_ 1024
// wkv chunked scan: 32 chunks of 16 steps
#define WKV_NCH 32
#define WKV_L 16

typedef __attribute__((ext_vector_type(8))) short bf16x8;
typedef __attribute__((ext_vector_type(4))) short s16x4;
typedef __attribute__((ext_vector_type(4))) float f32x4;

__device__ __forceinline__ float b2f(short u) {
  union { unsigned int i; float f; } x;
  x.i = ((unsigned int)(unsigned short)u) << 16;
  return x.f;
}
__device__ __forceinline__ short f2b(float f) {
  __hip_bfloat16 h = __float2bfloat16(f);  // RNE
  return __builtin_bit_cast(short, h);
}
__device__ __forceinline__ float sigm(float x) { return 1.0f / (1.0f + expf(-x)); }

// LIF over 4 identical inputs (closed form of the reference scan), TAU=2, VTH=1
__device__ __forceinline__ float lif4(float a) {
  float v = 0.0f, acc = 0.0f;
#pragma unroll
  for (int i = 0; i < 4; ++i) {
    v += (a - v) * 0.5f;
    float s = (v >= 1.0f) ? 1.0f : 0.0f;
    acc += s;
    v *= (1.0f - s);
  }
  return acc * 0.25f;
}

__device__ __forceinline__ void gload16(const void* g, void* l) {
  __builtin_amdgcn_global_load_lds(
      (__attribute__((address_space(1))) void*)(g),
      (__attribute__((address_space(3))) void*)(l), 16, 0, 0);
}

// counted vmcnt wait (compile-time immediate)
template <int N>
__device__ __forceinline__ void waitv() {
  if constexpr (N == 0)  asm volatile("s_waitcnt vmcnt(0)" ::: "memory");
  else if constexpr (N == 2)  asm volatile("s_waitcnt vmcnt(2)" ::: "memory");
  else if constexpr (N == 4)  asm volatile("s_waitcnt vmcnt(4)" ::: "memory");
  else if constexpr (N == 8)  asm volatile("s_waitcnt vmcnt(8)" ::: "memory");
  else if constexpr (N == 12) asm volatile("s_waitcnt vmcnt(12)" ::: "memory");
  else static_assert(N == 0, "unsupported vmcnt");
}
__device__ __forceinline__ void barrier_() {
  asm volatile("s_barrier" ::: "memory");
}

// ---------------- elementwise kernels ----------------

// fused concat + LayerNorm: row of xc = (t<256 ? x : rt); writes XC (f32 copy)
// and LN output (bf16). One 256-thread block per row (4096 rows).
__global__ __launch_bounds__(256) void ln_first(const float* __restrict__ x,
                                                const float* __restrict__ rt,
                                                float* __restrict__ xc,
                                                short* __restrict__ dst) {
  __shared__ float red[256];
  int row = blockIdx.x;  // b*512 + t
  int t = row & 511, b = row >> 9;
  const float* src = (t < 256) ? x + (int64_t)(b * 256 + t) * TC_
                               : rt + (int64_t)(t - 256) * TC_;
  float4 v = ((const float4*)src)[threadIdx.x];
  ((float4*)(xc + (int64_t)row * TC_))[threadIdx.x] = v;
  red[threadIdx.x] = v.x + v.y + v.z + v.w;
  __syncthreads();
  for (int off = 128; off > 0; off >>= 1) {
    if (threadIdx.x < off) red[threadIdx.x] += red[threadIdx.x + off];
    __syncthreads();
  }
  float mean = red[0] * (1.0f / 1024.0f);
  __syncthreads();
  float dx = v.x - mean, dy = v.y - mean, dz = v.z - mean, dw = v.w - mean;
  red[threadIdx.x] = dx * dx + dy * dy + dz * dz + dw * dw;
  __syncthreads();
  for (int off = 128; off > 0; off >>= 1) {
    if (threadIdx.x < off) red[threadIdx.x] += red[threadIdx.x + off];
    __syncthreads();
  }
  float rs = 1.0f / sqrtf(red[0] * (1.0f / 1024.0f) + 1e-6f);
  s16x4 o;
  o.x = f2b(dx * rs); o.y = f2b(dy * rs); o.z = f2b(dz * rs); o.w = f2b(dw * rs);
  *(s16x4*)(dst + (int64_t)row * TC_ + threadIdx.x * 4) = o;
}

// fused ln2 + channel-mix blend: per row r, compute LN(XC[r]) and LN(XC[r-1])
// (recompute; branch is block-uniform), blend with cmk/cmr, write bf16.
__global__ __launch_bounds__(256) void ln_mix2(const float* __restrict__ xc,
                                               const float* __restrict__ cmk,
                                               const float* __restrict__ cmr,
                                               short* __restrict__ xk,
                                               short* __restrict__ xr) {
  __shared__ float red[256];
  int row = blockIdx.x;
  int t = row & 511;
  int tid = threadIdx.x;
  // LN of current row
  float4 v = ((const float4*)(xc + (int64_t)row * TC_))[tid];
  red[tid] = v.x + v.y + v.z + v.w;
  __syncthreads();
  for (int off = 128; off > 0; off >>= 1) {
    if (tid < off) red[tid] += red[tid + off];
    __syncthreads();
  }
  float mean = red[0] * (1.0f / 1024.0f);
  __syncthreads();
  float dx = v.x - mean, dy = v.y - mean, dz = v.z - mean, dw = v.w - mean;
  red[tid] = dx * dx + dy * dy + dz * dz + dw * dw;
  __syncthreads();
  for (int off = 128; off > 0; off >>= 1) {
    if (tid < off) red[tid] += red[tid + off];
    __syncthreads();
  }
  float rs = 1.0f / sqrtf(red[0] * (1.0f / 1024.0f) + 1e-6f);
  float c0 = dx * rs, c1 = dy * rs, c2 = dz * rs, c3 = dw * rs;
  float p0 = 0.f, p1 = 0.f, p2 = 0.f, p3 = 0.f;
  if (t > 0) {  // block-uniform branch
    __syncthreads();
    float4 w4 = ((const float4*)(xc + (int64_t)(row - 1) * TC_))[tid];
    red[tid] = w4.x + w4.y + w4.z + w4.w;
    __syncthreads();
    for (int off = 128; off > 0; off >>= 1) {
      if (tid < off) red[tid] += red[tid + off];
      __syncthreads();
    }
    float meanp = red[0] * (1.0f / 1024.0f);
    __syncthreads();
    float ex = w4.x - meanp, ey = w4.y - meanp, ez = w4.z - meanp,
          ew = w4.w - meanp;
    red[tid] = ex * ex + ey * ey + ez * ez + ew * ew;
    __syncthreads();
    for (int off = 128; off > 0; off >>= 1) {
      if (tid < off) red[tid] += red[tid + off];
      __syncthreads();
    }
    float rsp = 1.0f / sqrtf(red[0] * (1.0f / 1024.0f) + 1e-6f);
    p0 = ex * rsp; p1 = ey * rsp; p2 = ez * rsp; p3 = ew * rsp;
  }
  int c = tid * 4;
  float k0 = cmk[c], k1 = cmk[c + 1], k2 = cmk[c + 2], k3 = cmk[c + 3];
  float r0 = cmr[c], r1 = cmr[c + 1], r2 = cmr[c + 2], r3 = cmr[c + 3];
  s16x4 ok, orr;
  ok.x = f2b(c0 * k0 + p0 * (1.0f - k0));
  ok.y = f2b(c1 * k1 + p1 * (1.0f - k1));
  ok.z = f2b(c2 * k2 + p2 * (1.0f - k2));
  ok.w = f2b(c3 * k3 + p3 * (1.0f - k3));
  orr.x = f2b(c0 * r0 + p0 * (1.0f - r0));
  orr.y = f2b(c1 * r1 + p1 * (1.0f - r1));
  orr.z = f2b(c2 * r2 + p2 * (1.0f - r2));
  orr.w = f2b(c3 * r3 + p3 * (1.0f - r3));
  *(s16x4*)(xk + (int64_t)row * TC_ + c) = ok;
  *(s16x4*)(xr + (int64_t)row * TC_ + c) = orr;
}

// time-mix blends from bf16 LN. 8 elems/thread; i over B*T*C/8.
__global__ __launch_bounds__(256) void mix3_b(const short* __restrict__ ln,
                                              const float* __restrict__ tk,
                                              const float* __restrict__ tv,
                                              const float* __restrict__ tr,
                                              short* __restrict__ xk,
                                              short* __restrict__ xv,
                                              short* __restrict__ xr) {
  int i = blockIdx.x * 256 + threadIdx.x;  // short8 index
  int c8 = i & 127;
  int t = (i >> 7) & 511;
  bf16x8 h = *(const bf16x8*)(ln + (int64_t)i * 8);
  bf16x8 s = {};
  if (t > 0) s = *(const bf16x8*)(ln + (int64_t)(i - 128) * 8);
  bf16x8 ok, ov, orr;
#pragma unroll
  for (int e = 0; e < 8; ++e) {
    float hf = b2f(h[e]), sf = b2f(s[e]);
    int c = c8 * 8 + e;
    float mk = tk[c], mv = tv[c], mr = tr[c];
    ok[e] = f2b(hf * mk + sf * (1.0f - mk));
    ov[e] = f2b(hf * mv + sf * (1.0f - mv));
    orr[e] = f2b(hf * mr + sf * (1.0f - mr));
  }
  *(bf16x8*)(xk + (int64_t)i * 8) = ok;
  *(bf16x8*)(xv + (int64_t)i * 8) = ov;
  *(bf16x8*)(xr + (int64_t)i * 8) = orr;
}

// f32 -> bf16, 8 elems/thread (used for Wck after its slot frees up)
__global__ __launch_bounds__(256) void cvt_b(const float* __restrict__ src,
                                             short* __restrict__ dst) {
  int64_t i = (int64_t)(blockIdx.x * 256 + threadIdx.x) * 8;
  float4 a = *(const float4*)(src + i);
  float4 b = *(const float4*)(src + i + 4);
  bf16x8 o;
  o[0] = f2b(a.x); o[1] = f2b(a.y); o[2] = f2b(a.z); o[3] = f2b(a.w);
  o[4] = f2b(b.x); o[5] = f2b(b.y); o[6] = f2b(b.z); o[7] = f2b(b.w);
  *(bf16x8*)(dst + i) = o;
}

// ONE launch: convert 8 weight arrays f32->bf16 + fused Wam row-sum.
__global__ __launch_bounds__(256) void cvt_all(
    const float* __restrict__ Wk, const float* __restrict__ Wv,
    const float* __restrict__ Wr, const float* __restrict__ Wo,
    const float* __restrict__ Wcr, const float* __restrict__ Wcv,
    const float* __restrict__ Wrm, const float* __restrict__ Wam,
    short* __restrict__ bWk, short* __restrict__ bWv, short* __restrict__ bWr,
    short* __restrict__ bWo, short* __restrict__ bWcr, short* __restrict__ bWcv,
    short* __restrict__ bWrm, short* __restrict__ bWam,
    float* __restrict__ S) {
  int bid = blockIdx.x;
  if (bid >= 4864) {  // Wam row-sums: 4 rows per block, 64 lanes per row
    int row = (bid - 4864) * 4 + (threadIdx.x >> 6);
    int lane = threadIdx.x & 63;
    float4 v = ((const float4*)(Wam + (int64_t)row * 256))[lane];
    float s = v.x + v.y + v.z + v.w;
    for (int off = 32; off > 0; off >>= 1) s += __shfl_down(s, off);
    if (lane == 0) S[row] = s;
    return;
  }
  const float* src; short* dst; int base;
  if (bid < 512)       { src = Wk;  dst = bWk;  base = bid; }
  else if (bid < 1024) { src = Wv;  dst = bWv;  base = bid - 512; }
  else if (bid < 1536) { src = Wr;  dst = bWr;  base = bid - 1024; }
  else if (bid < 2048) { src = Wo;  dst = bWo;  base = bid - 1536; }
  else if (bid < 2560) { src = Wcr; dst = bWcr; base = bid - 2048; }
  else if (bid < 4608) { src = Wcv; dst = bWcv; base = bid - 2560; }
  else if (bid < 4736) { src = Wrm; dst = bWrm; base = bid - 4608; }
  else                 { src = Wam; dst = bWam; base = bid - 4736; }
  int64_t i = ((int64_t)base * 256 + threadIdx.x) * 8;
  float4 a = *(const float4*)(src + i);
  float4 b = *(const float4*)(src + i + 4);
  bf16x8 o;
  o[0] = f2b(a.x); o[1] = f2b(a.y); o[2] = f2b(a.z); o[3] = f2b(a.w);
  o[4] = f2b(b.x); o[5] = f2b(b.y); o[6] = f2b(b.z); o[7] = f2b(b.w);
  *(bf16x8*)(dst + i) = o;
}

// ---------------- wkv chunked parallel scan ----------------
__global__ __launch_bounds__(256) void wkv_p1(const float* __restrict__ td,
                                              const short* __restrict__ K,
                                              const short* __restrict__ V,
                                              float* __restrict__ Ca,
                                              float* __restrict__ Da,
                                              float* __restrict__ Qa) {
  int bx = blockIdx.x;  // [ch:5][b:3][cg:2]
  int ch = bx >> 5;
  int b = (bx >> 2) & 7;
  int c = (bx & 3) * 256 + threadIdx.x;
  float w = -expf(td[c]);
  float aa = 0.0f, bb = 0.0f, pp = -1e38f;
  int64_t base = ((int64_t)b * TT_ + ch * WKV_L) * TC_ + c;
#pragma unroll
  for (int t = 0; t < WKV_L; ++t) {
    int64_t o = base + (int64_t)t * TC_;
    float kt = b2f(K[o]), vt = b2f(V[o]);
    float ww2 = pp + w;
    float p2 = fmaxf(ww2, kt);
    float e1 = expf(ww2 - p2);
    float e2 = expf(kt - p2);
    aa = e1 * aa + e2 * vt;
    bb = e1 * bb + e2;
    pp = p2;
  }
  int idx = ch * 8192 + b * 1024 + c;
  Ca[idx] = aa; Da[idx] = bb; Qa[idx] = pp;
}

__global__ __launch_bounds__(256) void wkv_p2(const float* __restrict__ td,
                                              const float* __restrict__ Ca,
                                              const float* __restrict__ Da,
                                              const float* __restrict__ Qa,
                                              float* __restrict__ Aa,
                                              float* __restrict__ Ba,
                                              float* __restrict__ Pa) {
  int i = blockIdx.x * 256 + threadIdx.x;  // 0..8191 = b*1024+c
  int c = i & (TC_ - 1);
  float wL = -expf(td[c]) * (float)WKV_L;
  float aa = 0.0f, bb = 0.0f, pp = -1e38f;
#pragma unroll 4
  for (int ch = 0; ch < WKV_NCH; ++ch) {
    int idx = ch * 8192 + i;
    Aa[idx] = aa; Ba[idx] = bb; Pa[idx] = pp;
    float ppw = pp + wL;
    float q = Qa[idx];
    float p2 = fmaxf(ppw, q);
    float ea = expf(ppw - p2);
    float eb = expf(q - p2);
    aa = aa * ea + Ca[idx] * eb;
    bb = bb * ea + Da[idx] * eb;
    pp = p2;
  }
}

__global__ __launch_bounds__(256) void wkv_p3(const float* __restrict__ td,
                                              const float* __restrict__ tf,
                                              const short* __restrict__ K,
                                              const short* __restrict__ V,
                                              const short* __restrict__ SR,
                                              short* __restrict__ SRY,
                                              const float* __restrict__ Aa,
                                              const float* __restrict__ Ba,
                                              const float* __restrict__ Pa) {
  int bx = blockIdx.x;
  int ch = bx >> 5;
  int b = (bx >> 2) & 7;
  int c = (bx & 3) * 256 + threadIdx.x;
  float w = -expf(td[c]);
  float u = tf[c];
  int idx = ch * 8192 + b * 1024 + c;
  float aa = Aa[idx], bb = Ba[idx], pp = Pa[idx];
  int64_t base = ((int64_t)b * TT_ + ch * WKV_L) * TC_ + c;
#pragma unroll
  for (int t = 0; t < WKV_L; ++t) {
    int64_t o = base + (int64_t)t * TC_;
    float kt = b2f(K[o]), vt = b2f(V[o]);
    float ww = u + kt;
    float p = fmaxf(pp, ww);
    float E1 = expf(pp - p);
    float E2 = expf(ww - p);
    float y = (E1 * aa + E2 * vt) / (E1 * bb + E2);
    SRY[o] = f2b(y * b2f(SR[o]));
    float ww2 = pp + w;
    float p2 = fmaxf(ww2, kt);
    float e1 = expf(ww2 - p2);
    float e2 = expf(kt - p2);
    aa = e1 * aa + e2 * vt;
    bb = e1 * bb + e2;
    pp = p2;
  }
}

// ---------------- LDS MFMA GEMM ----------------
// C[bz][m][n] = epi( sum_{k<K} A[m][k]*B[n][k] ), row stride Kst.
// BM x BN tile, BK=32, 256 threads (4 waves 2x2), depth-D LDS ring in MFMA
// lane order (0 bank conflicts) + counted-vmcnt pipeline. Measured best:
// 1 blk/CU -> D=4 (75us kv); >=3 blk/CU -> D=2 (m114 inter-block overlap).
// EPI: 1 sigmoid bf16; 2 relu^2 bf16; 0 bf16;
//      3 tail-final f32 (e0=brm[m], e1=S[n], e2=bam[n], e3=XC f32, sE);
//      4 C(f32) += lif4(acc);
//      5 C(f32) += lif4(acc*e3[m][n]), rows t>=256 also write bf16 rtok (e1);
//      6 z-select: bz==2 ? sigmoid : plain (bf16)
template <int BM, int BN, int EPI, int D, int MINW>
__global__ __launch_bounds__(256, MINW) void gemm_bf16(
    const short* __restrict__ A, const short* __restrict__ B,
    void* __restrict__ Cp, int M, int N, int K, int Kst,
    int64_t sA, int64_t sB, int64_t sC,
    const float* __restrict__ e0, const float* __restrict__ e1,
    const float* __restrict__ e2, const void* __restrict__ e3, int64_t sE) {
  constexpr int MF = BM / 32;
  constexpr int NF = BN / 32;
  constexpr int ASLOT = BM / 64;
  constexpr int BSLOT = BN / 64;
  constexpr int NL = ASLOT + BSLOT;
  constexpr int SBUF = (BM + BN) * 32;
  __shared__ short lds[D * SBUF];
  const int tid = threadIdx.x;

  // bijective XCD chunked swizzle (m204); requires nwg % 8 == 0
  const unsigned gx = gridDim.x, gy = gridDim.y;
  const unsigned nwg = gx * gy * gridDim.z;
  const unsigned lin = blockIdx.x + gx * (blockIdx.y + gy * blockIdx.z);
  const unsigned cs = nwg >> 3;
  const unsigned nl = (lin & 7) * cs + (lin >> 3);
  const unsigned bxs = nl % gx;
  const unsigned tmp = nl / gx;
  const unsigned bys = tmp % gy;
  const unsigned bz = tmp / gy;

  const int brow = bys * BM;
  const int bcol = bxs * BN;
  const short* Ab = A + bz * sA;
  const short* Bb = B + bz * sB;

  const int srow = ((tid >> 6) << 4) + (tid & 15);
  const int skc = ((tid >> 4) & 3) * 8;
  const short* gA[ASLOT];
  const short* gB[BSLOT];
#pragma unroll
  for (int s = 0; s < ASLOT; ++s)
    gA[s] = Ab + (int64_t)(brow + s * 64 + srow) * Kst + skc;
#pragma unroll
  for (int s = 0; s < BSLOT; ++s)
    gB[s] = Bb + (int64_t)(bcol + s * 64 + srow) * Kst + skc;

  const int lane = tid & 63, wid = tid >> 6;
  const int wr = wid >> 1, wc = wid & 1;

  f32x4 acc[MF][NF] = {};

  auto stage = [&](int buf, int k0) {
    short* d = lds + buf * SBUF;
#pragma unroll
    for (int s = 0; s < ASLOT; ++s)
      gload16(gA[s] + k0, d + s * 2048 + tid * 8);
#pragma unroll
    for (int s = 0; s < BSLOT; ++s)
      gload16(gB[s] + k0, d + BM * 32 + s * 2048 + tid * 8);
  };
  auto compute = [&](int buf) {
    const short* base = lds + buf * SBUF;
    bf16x8 af[MF], bfv[NF];
#pragma unroll
    for (int m = 0; m < MF; ++m)
      af[m] = *(const bf16x8*)(base + (wr * MF + m) * 512 + lane * 8);
#pragma unroll
    for (int n = 0; n < NF; ++n)
      bfv[n] = *(const bf16x8*)(base + BM * 32 + (wc * NF + n) * 512 + lane * 8);
#pragma unroll
    for (int m = 0; m < MF; ++m)
#pragma unroll
      for (int n = 0; n < NF; ++n)
        acc[m][n] = __builtin_amdgcn_mfma_f32_16x16x32_bf16(af[m], bfv[n],
                                                            acc[m][n], 0, 0, 0);
  };

  const int nst = K / 32;
#pragma unroll
  for (int d = 0; d < D - 1; ++d) stage(d, d * 32);
  for (int t = 0; t <= nst - D; ++t) {
    stage((t + D - 1) & (D - 1), (t + D - 1) * 32);
    waitv<(D - 1) * NL>();
    barrier_();
    compute(t & (D - 1));
    barrier_();
  }
  {
    int t = nst - D + 1;
    if constexpr (D >= 4) {
      waitv<2 * NL>(); barrier_(); compute(t & (D - 1)); barrier_(); ++t;
      waitv<1 * NL>(); barrier_(); compute(t & (D - 1)); barrier_(); ++t;
    }
    waitv<0>(); barrier_(); compute(t & (D - 1));
  }

  const int r0 = brow + wr * (BM / 2) + (lane >> 4) * 4;
  const int c0 = bcol + wc * (BN / 2) + (lane & 15);
#pragma unroll
  for (int m = 0; m < MF; ++m) {
#pragma unroll
    for (int j = 0; j < 4; ++j) {
      int row = r0 + m * 16 + j;
#pragma unroll
      for (int n = 0; n < NF; ++n) {
        int col = c0 + n * 16;
        float v = acc[m][n][j];
        int64_t idx = (int64_t)row * N + col;
        if (EPI == 0) {
          ((short*)Cp)[bz * sC + idx] = f2b(v);
        } else if (EPI == 1) {
          ((short*)Cp)[bz * sC + idx] = f2b(sigm(v));
        } else if (EPI == 2) {
          v = fmaxf(v, 0.0f);
          ((short*)Cp)[bz * sC + idx] = f2b(v * v);
        } else if (EPI == 3) {
          float r2 = v + e0[row] * e1[col] + e2[col];
          float xo = ((const float*)e3)[bz * sE + idx];
          ((float*)Cp)[bz * sC + idx] = xo * (1.0f + r2);
        } else if (EPI == 4) {
          float* XC = (float*)Cp;
          XC[idx] = XC[idx] + lif4(v);
        } else if (EPI == 5) {
          float* XC = (float*)Cp;
          float srr = b2f(((const short*)e3)[idx]);
          float nv = XC[idx] + lif4(v * srr);
          XC[idx] = nv;
          int tt = row & 511;
          if (tt >= 256) {  // fused rtok emit (b, t-256, col) bf16
            short* rtok = (short*)(void*)const_cast<float*>(e1);
            rtok[(((int64_t)(row >> 9)) * 256 + (tt - 256)) * 1024 + col] =
                f2b(nv);
          }
        } else if (EPI == 6) {
          ((short*)Cp)[bz * sC + idx] = f2b(bz == 2 ? sigm(v) : v);
        }
      }
    }
  }
}

// ---------------- launch ----------------
extern "C" void kernel_launch(void* const* d_in, const int* in_sizes, int n_in,
                              void* d_out, int out_size, void* d_ws,
                              size_t ws_size, hipStream_t stream) {
  const float* x   = (const float*)d_in[0];
  const float* rt  = (const float*)d_in[1];
  const float* td  = (const float*)d_in[2];
  const float* tf  = (const float*)d_in[3];
  const float* tmk = (const float*)d_in[4];
  const float* tmv = (const float*)d_in[5];
  const float* tmr = (const float*)d_in[6];
  const float* Wk  = (const float*)d_in[7];
  const float* Wv  = (const float*)d_in[8];
  const float* Wr  = (const float*)d_in[9];
  const float* Wo  = (const float*)d_in[10];
  const float* cmk = (const float*)d_in[11];
  const float* cmr = (const float*)d_in[12];
  const float* Wck = (const float*)d_in[13];
  const float* Wcv = (const float*)d_in[14];
  const float* Wcr = (const float*)d_in[15];
  const float* Wrm = (const float*)d_in[16];
  const float* brm = (const float*)d_in[17];
  const float* Wam = (const float*)d_in[18];
  const float* bam = (const float*)d_in[19];
  float* out = (float*)d_out;

  const size_t MB = 1ull << 20;
  uint8_t* W8 = (uint8_t*)d_ws;
  // Memory map (MB offsets), phase-ordered reuse (R8-proven layout):
  float* XC   = (float*)(W8);                        // 0-16 residual f32
  short* L    = (short*)(W8 + 16 * MB);              // 16-24 ln1 out
  short* S1   = (short*)(W8 + 24 * MB);              // 24-32 xk / SRY / SRR
  short* S2   = (short*)(W8 + 32 * MB);              // 32-40 xv / xk2 / rtok,Mt
  short* S3   = (short*)(W8 + 40 * MB);              // 40-48 xr / xr2 / bWck
  short* bWcv = (short*)(W8 + 48 * MB);              // 48-56
  short* bWk  = (short*)(W8 + 56 * MB);              // 56-62 bWk,bWv,bWr contig
  short* bWo  = (short*)(W8 + 62 * MB);
  short* bWcr = (short*)(W8 + 64 * MB);
  short* bWrm = (short*)(W8 + 66 * MB);              // 0.5 MB
  short* bWam = (short*)(W8 + 66 * MB + 512 * 1024); // 0.5 MB
  short* KK   = (short*)(W8 + 67 * MB);              // 67-75
  short* VV   = (short*)(W8 + 75 * MB);              // 75-83
  short* RR   = (short*)(W8 + 83 * MB);              // 83-91
  float* Ca   = (float*)(W8 + 91 * MB);              // wkv temps 91-97
  float* Da   = (float*)(W8 + 92 * MB);
  float* Qa   = (float*)(W8 + 93 * MB);
  float* Aa   = (float*)(W8 + 94 * MB);
  float* Ba   = (float*)(W8 + 95 * MB);
  float* Pa   = (float*)(W8 + 96 * MB);
  short* SRY  = S1;
  short* xk2  = S2;
  short* xr2  = S3;
  short* SRR  = S1;                                  // written step 6
  short* bWck = S3;                                  // after SRR GEMM
  short* H16  = KK;                                  // 67-99 (32 MB)
  short* rtok = S2;                                  // 32-36 (tail)
  short* Mt   = (short*)(W8 + 36 * MB);              // 36-37 (tail)
  float* Sb   = (float*)(W8 + 99 * MB);              // 4 KB, aliases nothing

  dim3 blk(256);
  const int NV8 = 2048;

  // 0) ALL weight conversions + Wam row-sum in one launch
  cvt_all<<<5120, blk, 0, stream>>>(Wk, Wv, Wr, Wo, Wcr, Wcv, Wrm, Wam,
                                    bWk, bWk + 1048576, bWk + 2097152, bWo,
                                    bWcr, bWcv, bWrm, bWam, Sb);

  // 1) fused concat+ln1 -> XC, L; mixes -> S1,S2,S3
  ln_first<<<TB_ * TT_, blk, 0, stream>>>(x, rt, XC, L);
  mix3_b<<<NV8, blk, 0, stream>>>(L, tmk, tmv, tmr, S1, S2, S3);

  // 2) fused z=3 time-mix: KK = xk*Wk^T, VV = xv*Wv^T, RR = sigm(xr*Wr^T)
  //    (grid 768 = 3 blk/CU, D=2)
  gemm_bf16<128, 128, 6, 2, 3><<<dim3(8, 32, 3), blk, 0, stream>>>(
      S1, bWk, KK, 4096, 1024, 1024, 1024, 4194304, 1048576, 4194304,
      nullptr, nullptr, nullptr, nullptr, 0);
  // 3) wkv chunked scan -> SRY (=S1)
  wkv_p1<<<WKV_NCH * TB_ * 4, blk, 0, stream>>>(td, KK, VV, Ca, Da, Qa);
  wkv_p2<<<32, blk, 0, stream>>>(td, Ca, Da, Qa, Aa, Ba, Pa);
  wkv_p3<<<WKV_NCH * TB_ * 4, blk, 0, stream>>>(td, tf, KK, VV, RR, SRY,
                                                Aa, Ba, Pa);
  // 4) att: XC += lif(SRY*Wo^T)   (1 blk/CU, measured-best D=4)
  gemm_bf16<128, 128, 4, 4, 2><<<dim3(8, 32, 1), blk, 0, stream>>>(
      SRY, bWo, XC, 4096, 1024, 1024, 1024, 0, 0, 0,
      nullptr, nullptr, nullptr, nullptr, 0);
  // 5) fused ln2+mix2 -> xk2(S2), xr2(S3)
  ln_mix2<<<TB_ * TT_, blk, 0, stream>>>(XC, cmk, cmr, xk2, xr2);
  // 6) SRR = sigm(xr2*Wcr^T) -> S1
  gemm_bf16<128, 128, 1, 4, 2><<<dim3(8, 32, 1), blk, 0, stream>>>(
      xr2, bWcr, SRR, 4096, 1024, 1024, 1024, 0, 0, 0,
      nullptr, nullptr, nullptr, nullptr, 0);
  // 7) Wck -> bf16 into now-dead xr2 slot
  cvt_b<<<2048, blk, 0, stream>>>(Wck, bWck);
  // 8) H = relu^2(xk2*Wck^T) -> H16 (grid 1024 = 4 blk/CU, D=2)
  gemm_bf16<128, 128, 2, 2, 4><<<dim3(32, 32, 1), blk, 0, stream>>>(
      xk2, bWck, H16, 4096, 4096, 1024, 1024, 0, 0, 0,
      nullptr, nullptr, nullptr, nullptr, 0);
  // 9) XC += lif(SRR*(H*Wcv^T)); rows t>=256 also emit rtok bf16 (fused)
  gemm_bf16<128, 128, 5, 4, 2><<<dim3(8, 32, 1), blk, 0, stream>>>(
      H16, bWcv, XC, 4096, 1024, 4096, 4096, 0, 0, 0,
      nullptr, (const float*)rtok, nullptr, SRR, 0);
  // 10) tail: Mt = Wrm x rtok^T per batch; out = xo*(1+Mt*Wam^T+brm*S+bam)
  gemm_bf16<64, 64, 0, 2, 2><<<dim3(4, 4, 8), blk, 0, stream>>>(
      bWrm, rtok, Mt, 256, 256, 1024, 1024, 0, (int64_t)256 * 1024,
      (int64_t)256 * 256, nullptr, nullptr, nullptr, nullptr, 0);
  gemm_bf16<64, 64, 3, 2, 2><<<dim3(16, 4, 8), blk, 0, stream>>>(
      Mt, bWam, out, 256, 1024, 256, 256, (int64_t)256 * 256, 0,
      (int64_t)256 * 1024, brm, Sb, bam, XC, (int64_t)512 * 1024);
}